// Round 1
// baseline (100.343 us; speedup 1.0000x reference)
//
#include <hip/hip_runtime.h>

#define K 32
#define RPB 64  // rows per block == block size (1 wave)

__device__ __forceinline__ float fast_tanh(float x) {
    // tanh(x) = (e^{2x}-1)/(e^{2x}+1); clamp so exp2 never overflows to inf
    x = fminf(20.0f, fmaxf(-20.0f, x));
    float t = __builtin_amdgcn_exp2f(x * 2.8853900817779268f); // 2*log2(e)
    return (t - 1.0f) * __builtin_amdgcn_rcpf(t + 1.0f);
}

__global__ __launch_bounds__(RPB) void metak_kernel(
    const int* __restrict__ vals, const float* __restrict__ dist,
    const float* __restrict__ w1, const float* __restrict__ b1,
    const float* __restrict__ w2, const float* __restrict__ b2,
    const float* __restrict__ fw1, const float* __restrict__ fb1,
    const float* __restrict__ fw2, const float* __restrict__ fb2,
    float* __restrict__ out)
{
    __shared__ float ld_d[RPB * 33];
    __shared__ int   ld_v[RPB * 33];
    const int tid = threadIdx.x;
    const int base = blockIdx.x * (RPB * K);

    // Coalesced staging: lane tid reads flat element it*64+tid (4B/lane, contiguous
    // 256B per wave instr), writes to padded LDS (stride 33 -> 2-way banks, free).
    #pragma unroll
    for (int it = 0; it < K; ++it) {
        int e = it * 64 + tid;
        int r = e >> 5, c = e & 31;
        ld_d[r * 33 + c] = dist[base + e];
        ld_v[r * 33 + c] = vals[base + e];
    }
    __syncthreads();

    // Pull my row into registers (stride-33 reads: bank (tid+i)%32 -> 2-way, free)
    float d[K]; int v[K];
    #pragma unroll
    for (int k = 0; k < K; ++k) {
        d[k] = ld_d[tid * 33 + k];
        v[k] = ld_v[tid * 33 + k];
    }

    // Distinct-nonzero prefix counts. 128-bit bitmask fast path (labels in [0,128)),
    // generic scan fallback otherwise (never taken for this dataset).
    float c[K];
    unsigned long long lo = 0ull, hi = 0ull;
    int cnt = 0;
    #pragma unroll
    for (int k = 0; k < K; ++k) {
        int x = v[k];
        if (x != 0) {
            if ((unsigned)x < 128u) {
                unsigned long long bit = 1ull << (x & 63);
                if (x < 64) { cnt += (lo & bit) ? 0 : 1; lo |= bit; }
                else        { cnt += (hi & bit) ? 0 : 1; hi |= bit; }
            } else {
                bool dup = false;
                #pragma unroll
                for (int j = 0; j < K; ++j) dup = dup || (j < k && v[j] == x);
                cnt += dup ? 0 : 1;
            }
        }
        c[k] = (float)cnt;
    }

    // fc2 layer 1: h[j] = b1[j] + sum_i in[i] * w1[i*32+j], in = [d(32), c(32)]
    // i-outer so each weight access is wave-uniform (scalarizable to s_load).
    float h[32];
    #pragma unroll
    for (int j = 0; j < 32; ++j) h[j] = b1[j];
    #pragma unroll
    for (int i = 0; i < 32; ++i) {
        float x = d[i];
        #pragma unroll
        for (int j = 0; j < 32; ++j) h[j] = fmaf(x, w1[i * 32 + j], h[j]);
    }
    #pragma unroll
    for (int i = 0; i < 32; ++i) {
        float x = c[i];
        #pragma unroll
        for (int j = 0; j < 32; ++j) h[j] = fmaf(x, w1[(32 + i) * 32 + j], h[j]);
    }

    // fc2 layer 2 (32 -> 2), tanh fused
    float o0 = b2[0], o1 = b2[1];
    #pragma unroll
    for (int j = 0; j < 32; ++j) {
        float th = fast_tanh(h[j]);
        o0 = fmaf(th, w2[j * 2 + 0], o0);
        o1 = fmaf(th, w2[j * 2 + 1], o1);
    }

    // fc1: (2 -> 4 tanh -> 1)
    float o2 = fb2[0];
    #pragma unroll
    for (int m = 0; m < 4; ++m) {
        float g = fast_tanh(fb1[m] + o0 * fw1[m] + o1 * fw1[4 + m]);
        o2 = fmaf(g, fw2[m], o2);
    }

    const int row = blockIdx.x * RPB + tid;
    out[row * 3 + 0] = o0;
    out[row * 3 + 1] = o1;
    out[row * 3 + 2] = o2;
}

extern "C" void kernel_launch(void* const* d_in, const int* in_sizes, int n_in,
                              void* d_out, int out_size, void* d_ws, size_t ws_size,
                              hipStream_t stream) {
    const int*   vals = (const int*)d_in[0];
    const float* dist = (const float*)d_in[1];
    const float* w1   = (const float*)d_in[2];
    const float* b1   = (const float*)d_in[3];
    const float* w2   = (const float*)d_in[4];
    const float* b2   = (const float*)d_in[5];
    const float* fw1  = (const float*)d_in[6];
    const float* fb1  = (const float*)d_in[7];
    const float* fw2  = (const float*)d_in[8];
    const float* fb2  = (const float*)d_in[9];
    float* out = (float*)d_out;

    const int rows   = in_sizes[0] / K;   // 32768
    const int blocks = rows / RPB;        // 512

    metak_kernel<<<blocks, RPB, 0, stream>>>(vals, dist, w1, b1, w2, b2,
                                             fw1, fb1, fw2, fb2, out);
}

// Round 2
// 84.211 us; speedup vs baseline: 1.1916x; 1.1916x over previous
//
#include <hip/hip_runtime.h>

#define K 32
#define TPR 4                 // threads cooperating per row (j-split of the matvec)
#define BLOCK 256
#define RPB (BLOCK / TPR)     // 64 rows per block

__device__ __forceinline__ float fast_tanh(float x) {
    // tanh(x) = (e^{2x}-1)/(e^{2x}+1); clamp so exp2 never overflows to inf
    x = fminf(20.0f, fmaxf(-20.0f, x));
    float t = __builtin_amdgcn_exp2f(x * 2.8853900817779268f); // 2*log2(e)
    return (t - 1.0f) * __builtin_amdgcn_rcpf(t + 1.0f);
}

__global__ __launch_bounds__(BLOCK) void metak_kernel(
    const int* __restrict__ vals, const float* __restrict__ dist,
    const float* __restrict__ w1, const float* __restrict__ b1,
    const float* __restrict__ w2, const float* __restrict__ b2,
    const float* __restrict__ fw1, const float* __restrict__ fb1,
    const float* __restrict__ fw2, const float* __restrict__ fb2,
    float* __restrict__ out)
{
    __shared__ float ld_d[RPB * 33];   // stride 33: staging writes & reads conflict-free
    __shared__ int   ld_v[RPB * 33];

    const int tid  = threadIdx.x;
    const int sub  = tid & (TPR - 1);  // which j-slice of the row
    const int rloc = tid >> 2;         // row within block, 0..63
    const int base = blockIdx.x * (RPB * K);

    // Coalesced staging: 64 rows x 32 elems = 2048 elems each; 256 threads x 8 iters.
    // addr = 33*r + c = e + r -> banks (e+r)%32: 2 lanes/bank per wave instr (free).
    #pragma unroll
    for (int it = 0; it < 8; ++it) {
        int e = it * BLOCK + tid;
        int r = e >> 5, c = e & 31;
        ld_d[r * 33 + c] = dist[base + e];
        ld_v[r * 33 + c] = vals[base + e];
    }
    __syncthreads();

    // Row inputs into registers. Quad lanes read identical addresses (broadcast);
    // across the 16 quads of a wave banks are (rloc + k) % 32 -> distinct.
    float d[K]; int v[K];
    #pragma unroll
    for (int k = 0; k < K; ++k) {
        d[k] = ld_d[rloc * 33 + k];
        v[k] = ld_v[rloc * 33 + k];
    }

    // Distinct-nonzero prefix counts (serial chain). Computed redundantly by all
    // 4 lanes of the quad -- divergence-free, no LDS round trip.
    float c[K];
    unsigned long long lo = 0ull, hi = 0ull;
    int cnt = 0;
    #pragma unroll
    for (int k = 0; k < K; ++k) {
        int x = v[k];
        if (x != 0) {
            if ((unsigned)x < 128u) {
                unsigned long long bit = 1ull << (x & 63);
                if (x < 64) { cnt += (lo & bit) ? 0 : 1; lo |= bit; }
                else        { cnt += (hi & bit) ? 0 : 1; hi |= bit; }
            } else {               // generic fallback (never taken for this data)
                bool dup = false;
                #pragma unroll
                for (int j = 0; j < K; ++j) dup = dup || (j < k && v[j] == x);
                cnt += dup ? 0 : 1;
            }
        }
        c[k] = (float)cnt;
    }

    // fc2 layer 1, j-slice: this thread computes h[j0..j0+7] over all 64 inputs.
    // Weight indices are wave-uniform (compile-time after unroll) -> s_load.
    const int j0 = sub * 8;
    float h[8];
    #pragma unroll
    for (int j = 0; j < 8; ++j) h[j] = b1[j0 + j];
    #pragma unroll
    for (int i = 0; i < K; ++i) {
        float x = d[i];
        #pragma unroll
        for (int j = 0; j < 8; ++j) h[j] = fmaf(x, w1[i * 32 + j0 + j], h[j]);
    }
    #pragma unroll
    for (int i = 0; i < K; ++i) {
        float x = c[i];
        #pragma unroll
        for (int j = 0; j < 8; ++j) h[j] = fmaf(x, w1[(K + i) * 32 + j0 + j], h[j]);
    }

    // Partial head dot-products over this slice, then quad butterfly reduce.
    float p0 = 0.0f, p1 = 0.0f;
    #pragma unroll
    for (int j = 0; j < 8; ++j) {
        float th = fast_tanh(h[j]);
        p0 = fmaf(th, w2[(j0 + j) * 2 + 0], p0);
        p1 = fmaf(th, w2[(j0 + j) * 2 + 1], p1);
    }
    p0 += __shfl_xor(p0, 1); p0 += __shfl_xor(p0, 2);
    p1 += __shfl_xor(p1, 1); p1 += __shfl_xor(p1, 2);
    const float o0 = p0 + b2[0];
    const float o1 = p1 + b2[1];

    // fc1 (2 -> 4 tanh -> 1), redundant on all 4 lanes (cheap, divergence-free).
    float o2 = fb2[0];
    #pragma unroll
    for (int m = 0; m < 4; ++m) {
        float g = fast_tanh(fb1[m] + o0 * fw1[m] + o1 * fw1[4 + m]);
        o2 = fmaf(g, fw2[m], o2);
    }

    // Lanes 0..2 of each quad store o0,o1,o2 for the row.
    const int row = blockIdx.x * RPB + rloc;
    float oval = (sub == 0) ? o0 : (sub == 1) ? o1 : o2;
    if (sub < 3) out[row * 3 + sub] = oval;
}

extern "C" void kernel_launch(void* const* d_in, const int* in_sizes, int n_in,
                              void* d_out, int out_size, void* d_ws, size_t ws_size,
                              hipStream_t stream) {
    const int*   vals = (const int*)d_in[0];
    const float* dist = (const float*)d_in[1];
    const float* w1   = (const float*)d_in[2];
    const float* b1   = (const float*)d_in[3];
    const float* w2   = (const float*)d_in[4];
    const float* b2   = (const float*)d_in[5];
    const float* fw1  = (const float*)d_in[6];
    const float* fb1  = (const float*)d_in[7];
    const float* fw2  = (const float*)d_in[8];
    const float* fb2  = (const float*)d_in[9];
    float* out = (float*)d_out;

    const int rows   = in_sizes[0] / K;     // 32768
    const int blocks = rows / RPB;          // 512 blocks x 256 threads = 2048 waves

    metak_kernel<<<blocks, BLOCK, 0, stream>>>(vals, dist, w1, b1, w2, b2,
                                               fw1, fb1, fw2, fb2, out);
}